// Round 1
// baseline (4876.046 us; speedup 1.0000x reference)
//
#include <hip/hip_runtime.h>
#include <math.h>

#define B_  64
#define H_  224
#define W_  224
#define C_  32
#define HW_ (H_ * W_)             // 50176
#define T_  16
#define TILES_ (W_ / T_)          // 14
#define NTILE_ (TILES_ * TILES_)  // 196
#define G_  512                   // persistent blocks: 2/CU on 256 CUs, guaranteed co-resident
#define SUMB_ 8                   // sum-owner blocks per sample (512/64)
#define PPO_ (HW_ / SUMB_)        // 6272 pixels per owner block

// ---------------------------------------------------------------------------
// Fused persistent kernel: per-sample pipeline {sum -> classify -> rotate}.
// Phase A (8 owner blocks / sample): partial spatial sums, atomicAdd to
//   sums[b*C..], then release-increment done[b].
// Phase B (196 blocks / sample): acquire-spin done[b-1]==8, recompute the
//   4-logit argmax locally (132 FLOP), rotate one 16x16 pixel tile.
// Rotate(b) runs within ~20-40 MB of traffic after sum(b) streamed sample b
// (6.4 MB) through L3 -> the rotate read is an L3 hit; x is read from HBM
// exactly once. Traffic floor: 411 MB read + 411 MB write.
// Deadlock-free by induction: waits at iteration b depend only on sum work
// placed at iterations <= b-1 of co-resident blocks; bounded spin as failsafe.
// ---------------------------------------------------------------------------
__global__ __launch_bounds__(256, 2)
void fused_kernel(const float* __restrict__ x,
                  const float* __restrict__ Wc,
                  const float* __restrict__ bc,
                  float* __restrict__ out,
                  float* __restrict__ sums,
                  int* __restrict__ done) {
    const int g = blockIdx.x;
    const int t = threadIdx.x;

    __shared__ float4 tile[T_ * T_ * 8];   // 32 KB; reused by both phases
    __shared__ int sk;

    const int own_b = g >> 3;   // sample whose sums this block owns
    const int own_c = g & 7;    // chunk within that sample

    for (int b = 0; b <= B_; ++b) {
        // ---------------- Phase A: sums for sample b ----------------
        if (b < B_ && own_b == b) {
            const int c4 = t & 7;   // float4 slot within pixel (channels 4*c4..)
            const int pr = t >> 3;  // 0..31 pixel-row group
            const float4* xb =
                (const float4*)(x + (size_t)b * HW_ * C_) + (size_t)own_c * PPO_ * 8;
            float4 acc = make_float4(0.f, 0.f, 0.f, 0.f);
#pragma unroll 8
            for (int it = 0; it < PPO_ / 32; ++it) {   // 196 iterations
                const float4 v = xb[(size_t)(pr + it * 32) * 8 + c4];
                acc.x += v.x; acc.y += v.y; acc.z += v.z; acc.w += v.w;
            }
            tile[t] = acc;
            __syncthreads();
#pragma unroll
            for (int stride = 128; stride >= 8; stride >>= 1) {
                if (t < stride) {
                    const float4 o = tile[t + stride];
                    tile[t].x += o.x; tile[t].y += o.y;
                    tile[t].z += o.z; tile[t].w += o.w;
                }
                __syncthreads();
            }
            if (t < 8) {
                const float4 v = tile[t];
                atomicAdd(&sums[b * C_ + t * 4 + 0], v.x);
                atomicAdd(&sums[b * C_ + t * 4 + 1], v.y);
                atomicAdd(&sums[b * C_ + t * 4 + 2], v.z);
                atomicAdd(&sums[b * C_ + t * 4 + 3], v.w);
            }
            __syncthreads();
            if (t == 0)
                __hip_atomic_fetch_add(&done[b], 1, __ATOMIC_RELEASE,
                                       __HIP_MEMORY_SCOPE_AGENT);
            __syncthreads();   // tile[] free for Phase B reuse
        }

        // ------------- Phase B: rotate one tile of sample b-1 -------------
        const int br = b - 1;
        if (br < 0) continue;                      // block-uniform
        int r = g - (br * NTILE_) % G_;            // per-sample block rotation
        if (r < 0) r += G_;
        if (r >= NTILE_) continue;                 // block-uniform

        if (t == 0) {
            int guard = 0;
            while (__hip_atomic_load(&done[br], __ATOMIC_ACQUIRE,
                                     __HIP_MEMORY_SCOPE_AGENT) < SUMB_) {
                __builtin_amdgcn_s_sleep(2);
                if (++guard > (1 << 20)) break;    // failsafe: never hang
            }
            // classify (jnp.argmax tie-break = first max -> strict >)
            const float inv = 1.0f / (float)HW_;
            float m[C_];
#pragma unroll
            for (int c = 0; c < C_; ++c)
                m[c] = __hip_atomic_load(&sums[br * C_ + c], __ATOMIC_RELAXED,
                                         __HIP_MEMORY_SCOPE_AGENT) * inv;
            float best = -INFINITY; int bi = 0;
#pragma unroll
            for (int j = 0; j < 4; ++j) {
                float l = bc[j];
#pragma unroll
                for (int c = 0; c < C_; ++c) l += m[c] * Wc[c * 4 + j];
                if (l > best) { best = l; bi = j; }
            }
            sk = bi;
        }
        __syncthreads();
        const int k = sk;

        // out[i][j] = x[si][sj]:
        //  k=0:(i,j)  k=1:(j, W-1-i)  k=2:(H-1-i, W-1-j)  k=3:(H-1-j, i)
        const int i0 = (r / TILES_) * T_;
        const int j0 = (r % TILES_) * T_;
        int sr0, sc0;
        switch (k) {
            case 0:  sr0 = i0;           sc0 = j0;           break;
            case 1:  sr0 = j0;           sc0 = W_ - T_ - i0; break;
            case 2:  sr0 = H_ - T_ - i0; sc0 = W_ - T_ - j0; break;
            default: sr0 = H_ - T_ - j0; sc0 = i0;           break;
        }
        const float4* xb = (const float4*)(x + (size_t)br * HW_ * C_);
        float4*       ob = (float4*)(out + (size_t)br * HW_ * C_);

        // Load: 2048 float4s, consecutive lanes -> consecutive bytes
        // (16 segments of 2 KB). Source tile is contiguous for every k.
#pragma unroll
        for (int rep = 0; rep < 8; ++rep) {
            const int lidx = rep * 256 + t;
            const int rr = lidx >> 7;
            const int cc = (lidx >> 3) & 15;
            const int c4 = lidx & 7;
            tile[lidx] = xb[((size_t)(sr0 + rr) * W_ + (sc0 + cc)) * 8 + c4];
        }
        __syncthreads();
        // Store: output row-major coalesced; in-tile gather via LDS.
#pragma unroll
        for (int rep = 0; rep < 8; ++rep) {
            const int oidx = rep * 256 + t;
            const int di = oidx >> 7;
            const int dj = (oidx >> 3) & 15;
            const int c4 = oidx & 7;
            int rr, cc;
            switch (k) {
                case 0:  rr = di;        cc = dj;        break;
                case 1:  rr = dj;        cc = 15 - di;   break;
                case 2:  rr = 15 - di;   cc = 15 - dj;   break;
                default: rr = 15 - dj;   cc = di;        break;
            }
            ob[((size_t)(i0 + di) * W_ + (j0 + dj)) * 8 + c4] =
                tile[(rr * 16 + cc) * 8 + c4];
        }
        __syncthreads();   // tile[] free for next iteration
    }
}

// ---------------------------------------------------------------------------
extern "C" void kernel_launch(void* const* d_in, const int* in_sizes, int n_in,
                              void* d_out, int out_size, void* d_ws, size_t ws_size,
                              hipStream_t stream) {
    const float* x  = (const float*)d_in[0];
    const float* Wc = (const float*)d_in[1];
    const float* bc = (const float*)d_in[2];
    float* out      = (float*)d_out;

    float* sums = (float*)d_ws;                                   // B_*C_ floats
    int*   done = (int*)((char*)d_ws + B_ * C_ * sizeof(float));  // B_ ints

    hipMemsetAsync(d_ws, 0, B_ * C_ * sizeof(float) + B_ * sizeof(int), stream);
    fused_kernel<<<G_, 256, 0, stream>>>(x, Wc, bc, out, sums, done);
}

// Round 2
// 1045.809 us; speedup vs baseline: 4.6625x; 4.6625x over previous
//
#include <hip/hip_runtime.h>
#include <math.h>

#define B_  64
#define H_  224
#define W_  224
#define C_  32
#define HW_ (H_ * W_)             // 50176
#define T_  16
#define TILES_ (W_ / T_)          // 14
#define NTILE_ (TILES_ * TILES_)  // 196
#define G_  512                   // persistent blocks: 2/CU on 256 CUs, co-resident
#define GRP_ 8                    // samples per pipeline stage
#define NSTAGE_ (B_ / GRP_)       // 8
#define BPS_ (G_ / GRP_)          // 64 sum blocks per sample
#define F4PS_ (HW_ * 8)           // 401408 float4 per sample
#define F4PB_ (F4PS_ / BPS_)      // 6272 float4 per block chunk (784 pixels)
#define TILES_STAGE_ (GRP_ * NTILE_)  // 1568 rotate tiles per stage

// ---------------------------------------------------------------------------
// Stage-pipelined fused kernel. Per stage s (8 samples = 51.4 MB):
//   Phase A: ALL 512 blocks sum group s (64 blocks/sample, contiguous 100 KB
//     chunk each, float4 coalesced) -> atomicAdd partials -> release done[b].
//     Sums are never gated => always make progress => deadlock-free.
//   Phase B: ALL 512 blocks rotate the 1568 tiles of group s-1 (~3 each).
//     Group s-1's x data was streamed <=155 MB of traffic ago => L3 hit.
//     Spin on done[b]==64 resolves in ~us since all 64 producers run
//     concurrently grid-wide (vs 8-block serial stage before: 70us/sample).
// HBM traffic: read x once (411 MB) + write out (411 MB).
// ---------------------------------------------------------------------------
__global__ __launch_bounds__(256, 2)
void fused_kernel(const float* __restrict__ x,
                  const float* __restrict__ Wc,
                  const float* __restrict__ bc,
                  float* __restrict__ out,
                  float* __restrict__ sums,
                  int* __restrict__ done) {
    const int g = blockIdx.x;
    const int t = threadIdx.x;

    __shared__ float4 tile[T_ * T_ * 8];   // 32 KB; reused by both phases
    __shared__ int sk;

    for (int s = 0; s <= NSTAGE_; ++s) {
        // ---------------- Phase A: sums for group s ----------------
        if (s < NSTAGE_) {
            const int b    = s * GRP_ + (g >> 6);   // g / BPS_
            const int chnk = g & (BPS_ - 1);
            const float4* xb = (const float4*)(x + (size_t)b * HW_ * C_)
                               + (size_t)chnk * F4PB_;
            // stride 256 (== 0 mod 8) keeps c4 = t&7 constant per thread.
            float4 acc = make_float4(0.f, 0.f, 0.f, 0.f);
#pragma unroll
            for (int j = 0; j < 25; ++j) {
                const int idx = j * 256 + t;
                if (idx < F4PB_) {                  // tail: j==24, t<128
                    const float4 v = xb[idx];
                    acc.x += v.x; acc.y += v.y; acc.z += v.z; acc.w += v.w;
                }
            }
            tile[t] = acc;
            __syncthreads();
#pragma unroll
            for (int stride = 128; stride >= 8; stride >>= 1) {
                if (t < stride) {
                    const float4 o = tile[t + stride];
                    tile[t].x += o.x; tile[t].y += o.y;
                    tile[t].z += o.z; tile[t].w += o.w;
                }
                __syncthreads();
            }
            if (t < 8) {
                const float4 v = tile[t];
                atomicAdd(&sums[b * C_ + t * 4 + 0], v.x);
                atomicAdd(&sums[b * C_ + t * 4 + 1], v.y);
                atomicAdd(&sums[b * C_ + t * 4 + 2], v.z);
                atomicAdd(&sums[b * C_ + t * 4 + 3], v.w);
            }
            __syncthreads();   // atomics issued before release; tile reusable
            if (t == 0)
                __hip_atomic_fetch_add(&done[b], 1, __ATOMIC_RELEASE,
                                       __HIP_MEMORY_SCOPE_AGENT);
        }

        // ------------- Phase B: rotate tiles of group s-1 -------------
        const int sp = s - 1;
        if (sp < 0) continue;                      // block-uniform

#pragma unroll 1
        for (int i = 0; i < 4; ++i) {
            const int w = i * G_ + g;              // tile id within stage
            if (w >= TILES_STAGE_) break;          // block-uniform
            const int br = sp * GRP_ + w / NTILE_;
            const int r  = w % NTILE_;

            if (t == 0) {
                int guard = 0;
                while (__hip_atomic_load(&done[br], __ATOMIC_ACQUIRE,
                                         __HIP_MEMORY_SCOPE_AGENT) < BPS_) {
                    __builtin_amdgcn_s_sleep(2);
                    if (++guard > (1 << 22)) break;   // failsafe: never hang
                }
                // classify (jnp.argmax tie-break = first max -> strict >)
                const float inv = 1.0f / (float)HW_;
                float m[C_];
#pragma unroll
                for (int c = 0; c < C_; ++c)
                    m[c] = __hip_atomic_load(&sums[br * C_ + c], __ATOMIC_RELAXED,
                                             __HIP_MEMORY_SCOPE_AGENT) * inv;
                float best = -INFINITY; int bi = 0;
#pragma unroll
                for (int j = 0; j < 4; ++j) {
                    float l = bc[j];
#pragma unroll
                    for (int c = 0; c < C_; ++c) l += m[c] * Wc[c * 4 + j];
                    if (l > best) { best = l; bi = j; }
                }
                sk = bi;
            }
            __syncthreads();
            const int k = sk;

            // out[i][j] = x[si][sj]:
            //  k=0:(i,j)  k=1:(j, W-1-i)  k=2:(H-1-i, W-1-j)  k=3:(H-1-j, i)
            const int i0 = (r / TILES_) * T_;
            const int j0 = (r % TILES_) * T_;
            int sr0, sc0;
            switch (k) {
                case 0:  sr0 = i0;           sc0 = j0;           break;
                case 1:  sr0 = j0;           sc0 = W_ - T_ - i0; break;
                case 2:  sr0 = H_ - T_ - i0; sc0 = W_ - T_ - j0; break;
                default: sr0 = H_ - T_ - j0; sc0 = i0;           break;
            }
            const float4* xb = (const float4*)(x + (size_t)br * HW_ * C_);
            float4*       ob = (float4*)(out + (size_t)br * HW_ * C_);

            // Load: 2048 float4s, consecutive lanes -> consecutive bytes
            // (16 segments of 2 KB). Source tile contiguous for every k.
#pragma unroll
            for (int rep = 0; rep < 8; ++rep) {
                const int lidx = rep * 256 + t;
                const int rr = lidx >> 7;
                const int cc = (lidx >> 3) & 15;
                const int c4 = lidx & 7;
                tile[lidx] = xb[((size_t)(sr0 + rr) * W_ + (sc0 + cc)) * 8 + c4];
            }
            __syncthreads();
            // Store: output row-major coalesced; in-tile gather via LDS.
#pragma unroll
            for (int rep = 0; rep < 8; ++rep) {
                const int oidx = rep * 256 + t;
                const int di = oidx >> 7;
                const int dj = (oidx >> 3) & 15;
                const int c4 = oidx & 7;
                int rr, cc;
                switch (k) {
                    case 0:  rr = di;        cc = dj;        break;
                    case 1:  rr = dj;        cc = 15 - di;   break;
                    case 2:  rr = 15 - di;   cc = 15 - dj;   break;
                    default: rr = 15 - dj;   cc = di;        break;
                }
                ob[((size_t)(i0 + di) * W_ + (j0 + dj)) * 8 + c4] =
                    tile[(rr * 16 + cc) * 8 + c4];
            }
            __syncthreads();   // tile[] free for next tile / next stage
        }
    }
}

// ---------------------------------------------------------------------------
extern "C" void kernel_launch(void* const* d_in, const int* in_sizes, int n_in,
                              void* d_out, int out_size, void* d_ws, size_t ws_size,
                              hipStream_t stream) {
    const float* x  = (const float*)d_in[0];
    const float* Wc = (const float*)d_in[1];
    const float* bc = (const float*)d_in[2];
    float* out      = (float*)d_out;

    float* sums = (float*)d_ws;                                   // B_*C_ floats
    int*   done = (int*)((char*)d_ws + B_ * C_ * sizeof(float));  // B_ ints

    hipMemsetAsync(d_ws, 0, B_ * C_ * sizeof(float) + B_ * sizeof(int), stream);
    fused_kernel<<<G_, 256, 0, stream>>>(x, Wc, bc, out, sums, done);
}